// Round 12
// baseline (2860.734 us; speedup 1.0000x reference)
//
#include <hip/hip_runtime.h>

typedef unsigned short u16;
typedef unsigned int u32;
typedef unsigned long long u64;

#define NB 8
#define NPTS 4096
#define MSEL 2048
#define NCENT (NB*MSEL)
#define KNBR 64
#define FEAT 64
#define FIN 67
#define HH 64
#define FOUT 128
#define CAND_CAP 192

#define KP1 96     // layer-1 K padded to 3x32
#define SA 104     // feat A-buffer row stride (bf16 elems)
#define S2 72      // h1/h2 row stride (within the wave's fA slab)

typedef __attribute__((ext_vector_type(8))) short short8;
typedef __attribute__((ext_vector_type(4))) float f32x4;

__device__ __forceinline__ float bf2f(u16 u) {
    union { u32 i; float f; } v; v.i = ((u32)u) << 16; return v.f;
}
__device__ __forceinline__ u16 f2bf(float f) {
    union { float f; u32 i; } v; v.f = f;
    u32 x = v.i;
    x += 0x7fffu + ((x >> 16) & 1u);
    return (u16)(x >> 16);
}
__device__ __forceinline__ void splitbf(float a, u16& hi, u16& lo) {
    u16 h = f2bf(a);
    hi = h;
    lo = f2bf(__fsub_rn(a, bf2f(h)));
}

// ---------------------------------------------------------------------------
// DPP wave-64 max reduce (verified r7-r11); result broadcast via readlane 63.
// ---------------------------------------------------------------------------
__device__ __forceinline__ int wave_max_i(int v) {
    int u;
    u = __builtin_amdgcn_update_dpp(v, v, 0x111, 0xf, 0xf, false); v = max(v, u);
    u = __builtin_amdgcn_update_dpp(v, v, 0x112, 0xf, 0xf, false); v = max(v, u);
    u = __builtin_amdgcn_update_dpp(v, v, 0x114, 0xf, 0xf, false); v = max(v, u);
    u = __builtin_amdgcn_update_dpp(v, v, 0x118, 0xf, 0xf, false); v = max(v, u);
    u = __builtin_amdgcn_update_dpp(v, v, 0x142, 0xf, 0xf, false); v = max(v, u);
    u = __builtin_amdgcn_update_dpp(v, v, 0x143, 0xf, 0xf, false); v = max(v, u);
    return __builtin_amdgcn_readlane(v, 63);
}

// ---------------------------------------------------------------------------
// Kernel 1: exact FPS. r10 structure (256 thr, carried coords, LDS hist, one
// barrier/step) with CONTIGUOUS point->thread mapping: thread t owns
// i in [16t, 16t+16). Per-thread ranges are disjoint & lane-ordered, so the
// wave's first-occurrence argmax = candidate of the FIRST lane achieving the
// max: ballot + ctz replaces the entire 6-stage DPP min-index chain. Wave
// order = index order, so the strict-> slot scan keeps exact semantics.
// Distance arithmetic bit-identical to r4-r11 (_rn ops, numpy sum order).
// ---------------------------------------------------------------------------
__global__ __launch_bounds__(256) void fps_kernel(const float* __restrict__ pos,
        int* __restrict__ sel, float* __restrict__ pos_out,
        float* __restrict__ batch_out) {
    __shared__ float px[NPTS], py[NPTS], pz[NPTS];
    __shared__ int hist[MSEL];
    __shared__ int sM[2][4], sI[2][4];
    __shared__ float sX[2][4], sY[2][4], sZ[2][4];
    const int b = blockIdx.x, t = threadIdx.x;
    const int lane = t & 63, wid = t >> 6;
    const float* pb = pos + (long)b * NPTS * 3;

    for (int i = t; i < NPTS; i += 256) {
        px[i] = pb[i*3+0]; py[i] = pb[i*3+1]; pz[i] = pb[i*3+2];
    }
    __syncthreads();

    float rx[16], ry[16], rz[16], md[16];
    #pragma unroll
    for (int j = 0; j < 16; ++j) {
        int i = (t << 4) | j;                 // contiguous chunk per thread
        rx[j] = px[i]; ry[j] = py[i]; rz[j] = pz[i];
        md[j] = __builtin_inff();
    }

    int cur = 0;
    float cx = px[0], cy = py[0], cz = pz[0];
    for (int s = 0; s < MSEL; ++s) {
        const int p = s & 1;
        if (t == 0) hist[s] = cur;
        float bv = -1.0f; int bj = 0;
        #pragma unroll
        for (int j = 0; j < 16; ++j) {
            float dx = __fsub_rn(rx[j], cx);
            float dy = __fsub_rn(ry[j], cy);
            float dz = __fsub_rn(rz[j], cz);
            float d  = __fadd_rn(__fadd_rn(__fmul_rn(dx,dx), __fmul_rn(dy,dy)),
                                 __fmul_rn(dz,dz));
            float m = fminf(md[j], d);
            md[j] = m;
            if (m > bv) { bv = m; bj = j; }   // strict >: smallest j = smallest i
        }
        const int fb = (int)__float_as_uint(bv);      // bv >= 0 -> int-ordered
        const int Mw = wave_max_i(fb);
        const u64 mask = __ballot(fb == Mw);
        const int L = (int)__builtin_ctzll(mask);     // first lane = smallest i
        if (lane == L) {                              // owner carries coords
            sM[p][wid] = Mw; sI[p][wid] = (t << 4) | bj;
            sX[p][wid] = rx[bj]; sY[p][wid] = ry[bj]; sZ[p][wid] = rz[bj];
        }
        __syncthreads();
        int M = sM[p][0], I = sI[p][0];
        float nx = sX[p][0], ny = sY[p][0], nz = sZ[p][0];
        #pragma unroll
        for (int w = 1; w < 4; ++w) {
            int Mo = sM[p][w];
            if (Mo > M) {                     // strict >: first wave = smallest i
                M = Mo; I = sI[p][w];
                nx = sX[p][w]; ny = sY[p][w]; nz = sZ[p][w];
            }
        }
        cur = I; cx = nx; cy = ny; cz = nz;
    }
    __syncthreads();
    for (int g = t; g < MSEL; g += 256) {
        int i = hist[g];
        int o = b * MSEL + g;
        sel[o] = i;
        pos_out[o*3+0] = px[i]; pos_out[o*3+1] = py[i]; pos_out[o*3+2] = pz[i];
        batch_out[o] = (float)b;
    }
}

// ---------------------------------------------------------------------------
// Kernel 1.5: weight pre-transform (unchanged, verified).
// ---------------------------------------------------------------------------
__global__ __launch_bounds__(256) void wcvt_kernel(const float* __restrict__ W1,
        const float* __restrict__ W2, const float* __restrict__ W3,
        u16* __restrict__ w1h, u16* __restrict__ w1l,
        u16* __restrict__ w2h, u16* __restrict__ w2l,
        u16* __restrict__ w3h, u16* __restrict__ w3l) {
    int t = blockIdx.x * 256 + threadIdx.x;
    if (t < 64*KP1) {
        int n = t / KP1, k = t % KP1;
        u16 h, l; splitbf((k < FIN) ? W1[(long)k*HH + n] : 0.0f, h, l);
        w1h[t] = h; w1l[t] = l;
    }
    if (t < 64*64) {
        int n = t / 64, k = t % 64;
        u16 h, l; splitbf(W2[(long)k*HH + n], h, l);
        w2h[t] = h; w2l[t] = l;
    }
    if (t < 128*64) {
        int n = t / 64, k = t % 64;
        u16 h, l; splitbf(W3[(long)k*FOUT + n], h, l);
        w3h[t] = h; w3l[t] = l;
    }
}

// ---------------------------------------------------------------------------
// Kernel 2: fused radius + PointNetConv + max-pool, barrier-free MLP with
// wave-slab h1/h2 overlay (r11, absmax-verified). NEW: depth-1 software
// pipeline on the B-fragment global loads (prefetch nc+1 while MFMAing nc)
// to hide the ~200-cyc L2 latency per nc-iteration. MFMA inputs and order
// bit-identical to r10/r11 (absmax tripwire: exactly 0.015625).
// ---------------------------------------------------------------------------
__global__ __launch_bounds__(256) void conv_kernel(const float* __restrict__ x,
        const float* __restrict__ pos, const int* __restrict__ sel,
        const u16* __restrict__ w1h, const u16* __restrict__ w1l,
        const u16* __restrict__ w2h, const u16* __restrict__ w2l,
        const u16* __restrict__ w3h, const u16* __restrict__ w3l,
        const float* __restrict__ b1, const float* __restrict__ b2,
        const float* __restrict__ b3, float* __restrict__ xout) {
    __shared__ __align__(16) u16 fAh[64*SA], fAl[64*SA];   // feat, then h1/h2 per-wave
    __shared__ float cdv[CAND_CAP];
    __shared__ int   cixv[CAND_CAP];
    __shared__ int   snbr[KNBR];
    __shared__ float poolw[4][FOUT];
    __shared__ int   sc[2];
    const int c = blockIdx.x, t = threadIdx.x;
    const int b = c >> 11;
    const int lane = t & 63, w = t >> 6;
    const int colc = lane & 15;
    const float* pb = pos + (long)b * NPTS * 3;
    const int j0 = sel[c];
    const float qx = pb[j0*3+0], qy = pb[j0*3+1], qz = pb[j0*3+2];

    float bias1[4], bias2[4], bias3[8];
    #pragma unroll
    for (int nc = 0; nc < 4; ++nc) { bias1[nc] = b1[nc*16+colc]; bias2[nc] = b2[nc*16+colc]; }
    #pragma unroll
    for (int nc = 0; nc < 8; ++nc) bias3[nc] = b3[nc*16+colc];

    if (t == 0) { sc[0] = 0; sc[1] = 0; }
    __syncthreads();

    // ---- radius gather (bit-exact; verified r4-r11)
    const float R2 = (float)(0.15 * 0.15);
    for (int it = 0; it < NPTS/256; ++it) {
        int i = t + 256*it;
        float dx = __fsub_rn(qx, pb[i*3+0]);
        float dy = __fsub_rn(qy, pb[i*3+1]);
        float dz = __fsub_rn(qz, pb[i*3+2]);
        float d2 = __fadd_rn(__fadd_rn(__fmul_rn(dx,dx), __fmul_rn(dy,dy)),
                             __fmul_rn(dz,dz));
        if (d2 <= R2) {
            int slot = atomicAdd(&sc[0], 1);
            if (slot < CAND_CAP) { cdv[slot] = d2; cixv[slot] = i; }
        }
    }
    __syncthreads();
    int C = sc[0]; if (C > CAND_CAP) C = CAND_CAP;
    int cnt;
    if (C <= KNBR) {
        for (int e = t; e < C; e += 256) snbr[e] = cixv[e];
        cnt = C;
    } else {
        for (int e = t; e < C; e += 256) {
            float de = cdv[e]; int ie = cixv[e];
            int rank = 0;
            for (int f = 0; f < C; ++f) {
                float df = cdv[f]; int jf = cixv[f];
                rank += (df < de || (df == de && jf < ie)) ? 1 : 0;
            }
            if (rank < KNBR) {
                int slot = atomicAdd(&sc[1], 1);
                snbr[slot] = ie;
            }
        }
        cnt = KNBR;
    }
    __syncthreads();

    // ---- stage features (wave-local rows); zero K-pad cols 67..99
    const int kk = t >> 2, sub = t & 3;
    if (kk < cnt) {
        int j = snbr[kk];
        const float4* xr4 = (const float4*)(x + ((long)b*NPTS + j) * FEAT);
        #pragma unroll
        for (int i = 0; i < 4; ++i) {
            int ci = sub*4 + i;
            float4 v = xr4[ci];
            u16 h0,l0,h1_,l1_,h2_,l2_,h3_,l3_;
            splitbf(v.x, h0, l0); splitbf(v.y, h1_, l1_);
            splitbf(v.z, h2_, l2_); splitbf(v.w, h3_, l3_);
            int o = kk*SA + ci*4;
            fAh[o+0]=h0; fAh[o+1]=h1_; fAh[o+2]=h2_; fAh[o+3]=h3_;
            fAl[o+0]=l0; fAl[o+1]=l1_; fAl[o+2]=l2_; fAl[o+3]=l3_;
        }
        if (sub < 3) {
            float qv = (sub == 0) ? qx : ((sub == 1) ? qy : qz);
            u16 h, l; splitbf(__fsub_rn(pb[j*3+sub], qv), h, l);
            fAh[kk*SA + 64 + sub] = h; fAl[kk*SA + 64 + sub] = l;
        } else {
            fAh[kk*SA + 67] = 0; fAl[kk*SA + 67] = 0;
        }
        u32* zh = (u32*)&fAh[kk*SA + 68];
        u32* zl = (u32*)&fAl[kk*SA + 68];
        #pragma unroll
        for (int i2 = 0; i2 < 4; ++i2) { zh[sub + 4*i2] = 0; zl[sub + 4*i2] = 0; }
    }
    __threadfence_block();

    const int mrow = w * 16;
    const int mA = mrow + (lane & 15);
    const int kq = (lane >> 4) * 8;
    const int rgrp = (lane >> 4) * 4;
    const int sb = mrow * SA;

    // ---- layer 1: 96(67) -> 64, B-frag prefetch pipeline
    short8 a1h[3], a1l[3];
    #pragma unroll
    for (int i = 0; i < 3; ++i) {
        a1h[i] = *(const short8*)&fAh[mA*SA + i*32 + kq];
        a1l[i] = *(const short8*)&fAl[mA*SA + i*32 + kq];
    }
    short8 cbh[3], cbl[3], nbh[3], nbl[3];
    #pragma unroll
    for (int i = 0; i < 3; ++i) {
        cbh[i] = *(const short8*)&w1h[(0*16+colc)*KP1 + i*32 + kq];
        cbl[i] = *(const short8*)&w1l[(0*16+colc)*KP1 + i*32 + kq];
    }
    #pragma unroll
    for (int nc = 0; nc < 4; ++nc) {
        if (nc < 3) {
            int n1 = (nc+1)*16 + colc;
            #pragma unroll
            for (int i = 0; i < 3; ++i) {
                nbh[i] = *(const short8*)&w1h[n1*KP1 + i*32 + kq];
                nbl[i] = *(const short8*)&w1l[n1*KP1 + i*32 + kq];
            }
        }
        int n = nc*16 + colc;
        float bb = bias1[nc];
        f32x4 acc = {bb, bb, bb, bb};
        #pragma unroll
        for (int i = 0; i < 3; ++i)
            acc = __builtin_amdgcn_mfma_f32_16x16x32_bf16(a1h[i], cbh[i], acc, 0,0,0);
        #pragma unroll
        for (int i = 0; i < 3; ++i)
            acc = __builtin_amdgcn_mfma_f32_16x16x32_bf16(a1h[i], cbl[i], acc, 0,0,0);
        #pragma unroll
        for (int i = 0; i < 3; ++i)
            acc = __builtin_amdgcn_mfma_f32_16x16x32_bf16(a1l[i], cbh[i], acc, 0,0,0);
        #pragma unroll
        for (int r = 0; r < 4; ++r) {
            u16 h, l; splitbf(fmaxf(acc[r], 0.0f), h, l);
            int mr = rgrp + r;
            fAh[sb + mr*S2 + n] = h; fAl[sb + mr*S2 + n] = l;
        }
        #pragma unroll
        for (int i = 0; i < 3; ++i) { cbh[i] = nbh[i]; cbl[i] = nbl[i]; }
    }
    __threadfence_block();

    // ---- layer 2: 64 -> 64 (h2 overwrites same slab)
    short8 a2h[2], a2l[2];
    #pragma unroll
    for (int i = 0; i < 2; ++i) {
        a2h[i] = *(const short8*)&fAh[sb + (lane&15)*S2 + i*32 + kq];
        a2l[i] = *(const short8*)&fAl[sb + (lane&15)*S2 + i*32 + kq];
    }
    short8 c2h[2], c2l[2], n2h[2], n2l[2];
    #pragma unroll
    for (int i = 0; i < 2; ++i) {
        c2h[i] = *(const short8*)&w2h[(0*16+colc)*64 + i*32 + kq];
        c2l[i] = *(const short8*)&w2l[(0*16+colc)*64 + i*32 + kq];
    }
    #pragma unroll
    for (int nc = 0; nc < 4; ++nc) {
        if (nc < 3) {
            int n1 = (nc+1)*16 + colc;
            #pragma unroll
            for (int i = 0; i < 2; ++i) {
                n2h[i] = *(const short8*)&w2h[n1*64 + i*32 + kq];
                n2l[i] = *(const short8*)&w2l[n1*64 + i*32 + kq];
            }
        }
        int n = nc*16 + colc;
        float bb = bias2[nc];
        f32x4 acc = {bb, bb, bb, bb};
        #pragma unroll
        for (int i = 0; i < 2; ++i)
            acc = __builtin_amdgcn_mfma_f32_16x16x32_bf16(a2h[i], c2h[i], acc, 0,0,0);
        #pragma unroll
        for (int i = 0; i < 2; ++i)
            acc = __builtin_amdgcn_mfma_f32_16x16x32_bf16(a2h[i], c2l[i], acc, 0,0,0);
        #pragma unroll
        for (int i = 0; i < 2; ++i)
            acc = __builtin_amdgcn_mfma_f32_16x16x32_bf16(a2l[i], c2h[i], acc, 0,0,0);
        #pragma unroll
        for (int r = 0; r < 4; ++r) {
            u16 h, l; splitbf(fmaxf(acc[r], 0.0f), h, l);
            int mr = rgrp + r;
            fAh[sb + mr*S2 + n] = h; fAl[sb + mr*S2 + n] = l;
        }
        #pragma unroll
        for (int i = 0; i < 2; ++i) { c2h[i] = n2h[i]; c2l[i] = n2l[i]; }
    }
    __threadfence_block();

    // ---- layer 3: 64 -> 128 + fused relu + masked max-pool
    short8 a3h[2], a3l[2];
    #pragma unroll
    for (int i = 0; i < 2; ++i) {
        a3h[i] = *(const short8*)&fAh[sb + (lane&15)*S2 + i*32 + kq];
        a3l[i] = *(const short8*)&fAl[sb + (lane&15)*S2 + i*32 + kq];
    }
    short8 c3h[2], c3l[2], n3h[2], n3l[2];
    #pragma unroll
    for (int i = 0; i < 2; ++i) {
        c3h[i] = *(const short8*)&w3h[(0*16+colc)*64 + i*32 + kq];
        c3l[i] = *(const short8*)&w3l[(0*16+colc)*64 + i*32 + kq];
    }
    #pragma unroll
    for (int nc = 0; nc < 8; ++nc) {
        if (nc < 7) {
            int n1 = (nc+1)*16 + colc;
            #pragma unroll
            for (int i = 0; i < 2; ++i) {
                n3h[i] = *(const short8*)&w3h[n1*64 + i*32 + kq];
                n3l[i] = *(const short8*)&w3l[n1*64 + i*32 + kq];
            }
        }
        int n = nc*16 + colc;
        float bb = bias3[nc];
        f32x4 acc = {bb, bb, bb, bb};
        #pragma unroll
        for (int i = 0; i < 2; ++i)
            acc = __builtin_amdgcn_mfma_f32_16x16x32_bf16(a3h[i], c3h[i], acc, 0,0,0);
        #pragma unroll
        for (int i = 0; i < 2; ++i)
            acc = __builtin_amdgcn_mfma_f32_16x16x32_bf16(a3h[i], c3l[i], acc, 0,0,0);
        #pragma unroll
        for (int i = 0; i < 2; ++i)
            acc = __builtin_amdgcn_mfma_f32_16x16x32_bf16(a3l[i], c3h[i], acc, 0,0,0);
        float v = 0.0f;   // relu >= 0 and cnt >= 1 -> 0 is identity
        #pragma unroll
        for (int r = 0; r < 4; ++r) {
            int m = mrow + rgrp + r;
            float hv = fmaxf(acc[r], 0.0f);
            v = (m < cnt) ? fmaxf(v, hv) : v;
        }
        v = fmaxf(v, __shfl_xor(v, 16, 64));
        v = fmaxf(v, __shfl_xor(v, 32, 64));
        if (lane < 16) poolw[w][nc*16 + lane] = v;
        #pragma unroll
        for (int i = 0; i < 2; ++i) { c3h[i] = n3h[i]; c3l[i] = n3l[i]; }
    }
    __syncthreads();
    if (t < FOUT) {
        float v = fmaxf(fmaxf(poolw[0][t], poolw[1][t]),
                        fmaxf(poolw[2][t], poolw[3][t]));
        xout[(long)c*FOUT + t] = v;
    }
}

// ---------------------------------------------------------------------------
extern "C" void kernel_launch(void* const* d_in, const int* in_sizes, int n_in,
                              void* d_out, int out_size, void* d_ws, size_t ws_size,
                              hipStream_t stream) {
    const float* x   = (const float*)d_in[0];
    const float* pos = (const float*)d_in[1];
    const float* W1 = (const float*)d_in[3];
    const float* b1 = (const float*)d_in[4];
    const float* W2 = (const float*)d_in[5];
    const float* b2 = (const float*)d_in[6];
    const float* W3 = (const float*)d_in[7];
    const float* b3 = (const float*)d_in[8];

    float* out       = (float*)d_out;
    float* xout      = out;
    float* pos_out   = out + (long)NCENT * FOUT;
    float* batch_out = pos_out + (long)NCENT * 3;

    int* sel = (int*)d_ws;
    u16* w1h = (u16*)((char*)d_ws + 65536);
    u16* w1l = w1h + 64*KP1;
    u16* w2h = w1l + 64*KP1;
    u16* w2l = w2h + 64*64;
    u16* w3h = w2l + 64*64;
    u16* w3l = w3h + 128*64;

    wcvt_kernel<<<32, 256, 0, stream>>>(W1, W2, W3, w1h, w1l, w2h, w2l, w3h, w3l);
    fps_kernel<<<NB, 256, 0, stream>>>(pos, sel, pos_out, batch_out);
    conv_kernel<<<NCENT, 256, 0, stream>>>(x, pos, sel, w1h, w1l, w2h, w2l,
                                           w3h, w3l, b1, b2, b3, xout);
}

// Round 13
// 2199.398 us; speedup vs baseline: 1.3007x; 1.3007x over previous
//
#include <hip/hip_runtime.h>

typedef unsigned short u16;
typedef unsigned int u32;
typedef unsigned long long u64;

#define NB 8
#define NPTS 4096
#define MSEL 2048
#define NCENT (NB*MSEL)
#define KNBR 64
#define FEAT 64
#define FIN 67
#define HH 64
#define FOUT 128
#define CAND_CAP 192

#define KP1 96     // layer-1 K padded to 3x32
#define SA 104     // feat A-buffer row stride (bf16 elems)
#define S2 72      // h1/h2 row stride (within the wave's fA slab)

typedef __attribute__((ext_vector_type(8))) short short8;
typedef __attribute__((ext_vector_type(4))) float f32x4;

__device__ __forceinline__ float bf2f(u16 u) {
    union { u32 i; float f; } v; v.i = ((u32)u) << 16; return v.f;
}
__device__ __forceinline__ u16 f2bf(float f) {
    union { float f; u32 i; } v; v.f = f;
    u32 x = v.i;
    x += 0x7fffu + ((x >> 16) & 1u);
    return (u16)(x >> 16);
}
__device__ __forceinline__ void splitbf(float a, u16& hi, u16& lo) {
    u16 h = f2bf(a);
    hi = h;
    lo = f2bf(__fsub_rn(a, bf2f(h)));
}

// ---------------------------------------------------------------------------
// DPP wave-64 reductions (verified r7-r11).
// ---------------------------------------------------------------------------
__device__ __forceinline__ int wave_max_i(int v) {
    int u;
    u = __builtin_amdgcn_update_dpp(v, v, 0x111, 0xf, 0xf, false); v = max(v, u);
    u = __builtin_amdgcn_update_dpp(v, v, 0x112, 0xf, 0xf, false); v = max(v, u);
    u = __builtin_amdgcn_update_dpp(v, v, 0x114, 0xf, 0xf, false); v = max(v, u);
    u = __builtin_amdgcn_update_dpp(v, v, 0x118, 0xf, 0xf, false); v = max(v, u);
    u = __builtin_amdgcn_update_dpp(v, v, 0x142, 0xf, 0xf, false); v = max(v, u);
    u = __builtin_amdgcn_update_dpp(v, v, 0x143, 0xf, 0xf, false); v = max(v, u);
    return __builtin_amdgcn_readlane(v, 63);
}
__device__ __forceinline__ int wave_min_i(int v) {
    int u;
    u = __builtin_amdgcn_update_dpp(v, v, 0x111, 0xf, 0xf, false); v = min(v, u);
    u = __builtin_amdgcn_update_dpp(v, v, 0x112, 0xf, 0xf, false); v = min(v, u);
    u = __builtin_amdgcn_update_dpp(v, v, 0x114, 0xf, 0xf, false); v = min(v, u);
    u = __builtin_amdgcn_update_dpp(v, v, 0x118, 0xf, 0xf, false); v = min(v, u);
    u = __builtin_amdgcn_update_dpp(v, v, 0x142, 0xf, 0xf, false); v = min(v, u);
    u = __builtin_amdgcn_update_dpp(v, v, 0x143, 0xf, 0xf, false); v = min(v, u);
    return __builtin_amdgcn_readlane(v, 63);
}

// ---------------------------------------------------------------------------
// Kernel 1: exact FPS == r10 (best measured: 1722 us) with the slot arrays
// repacked into int4 + float slabs so the post-barrier read burst is
// 4x ds_read_b128 + 4x ds_read_b32 instead of 20 scalar dwords. Same values,
// same strict-> / min-index scan — semantics bit-identical to r10
// (verified absmax 0.0 rounds 4-11 on pos_out).
// ---------------------------------------------------------------------------
__global__ __launch_bounds__(256) void fps_kernel(const float* __restrict__ pos,
        int* __restrict__ sel, float* __restrict__ pos_out,
        float* __restrict__ batch_out) {
    __shared__ float px[NPTS], py[NPTS], pz[NPTS];
    __shared__ int hist[MSEL];
    __shared__ int4  sA[2][4];    // {M, I, xbits, ybits} per wave
    __shared__ float sZ[2][4];
    const int b = blockIdx.x, t = threadIdx.x;
    const int wid = t >> 6;
    const float* pb = pos + (long)b * NPTS * 3;

    for (int i = t; i < NPTS; i += 256) {
        px[i] = pb[i*3+0]; py[i] = pb[i*3+1]; pz[i] = pb[i*3+2];
    }
    __syncthreads();

    float rx[16], ry[16], rz[16], md[16];
    #pragma unroll
    for (int j = 0; j < 16; ++j) {
        int i = t + 256*j;
        rx[j] = px[i]; ry[j] = py[i]; rz[j] = pz[i];
        md[j] = __builtin_inff();
    }

    int cur = 0;
    float cx = px[0], cy = py[0], cz = pz[0];
    for (int s = 0; s < MSEL; ++s) {
        const int p = s & 1;
        if (t == 0) hist[s] = cur;
        float bv = -1.0f; int bi = 0;
        #pragma unroll
        for (int j = 0; j < 16; ++j) {
            float dx = __fsub_rn(rx[j], cx);
            float dy = __fsub_rn(ry[j], cy);
            float dz = __fsub_rn(rz[j], cz);
            float d  = __fadd_rn(__fadd_rn(__fmul_rn(dx,dx), __fmul_rn(dy,dy)),
                                 __fmul_rn(dz,dz));
            float m = fminf(md[j], d);
            md[j] = m;
            if (m > bv) { bv = m; bi = t + 256*j; }   // strict >: first occurrence
        }
        const int fb = (int)__float_as_uint(bv);       // bv >= 0 -> int-ordered
        const int Mw = wave_max_i(fb);
        const int cnd = (fb == Mw) ? bi : 0x7fffffff;
        const int Iw = wave_min_i(cnd);                // wave argmax, min index
        if (t == (Iw & 255)) {                         // owner carries coords
            int j = Iw >> 8;
            sA[p][wid] = make_int4(Mw, Iw, __float_as_int(rx[j]),
                                   __float_as_int(ry[j]));
            sZ[p][wid] = rz[j];
        }
        __syncthreads();
        int4 v0 = sA[p][0];
        int M = v0.x, I = v0.y;
        float nx = __int_as_float(v0.z), ny = __int_as_float(v0.w), nz = sZ[p][0];
        #pragma unroll
        for (int w = 1; w < 4; ++w) {
            int4 vw = sA[p][w];
            if (vw.x > M || (vw.x == M && vw.y < I)) {
                M = vw.x; I = vw.y;
                nx = __int_as_float(vw.z); ny = __int_as_float(vw.w);
                nz = sZ[p][w];
            }
        }
        cur = I; cx = nx; cy = ny; cz = nz;
    }
    __syncthreads();
    for (int g = t; g < MSEL; g += 256) {
        int i = hist[g];
        int o = b * MSEL + g;
        sel[o] = i;
        pos_out[o*3+0] = px[i]; pos_out[o*3+1] = py[i]; pos_out[o*3+2] = pz[i];
        batch_out[o] = (float)b;
    }
}

// ---------------------------------------------------------------------------
// Kernel 1.5: weight pre-transform (unchanged, verified).
// ---------------------------------------------------------------------------
__global__ __launch_bounds__(256) void wcvt_kernel(const float* __restrict__ W1,
        const float* __restrict__ W2, const float* __restrict__ W3,
        u16* __restrict__ w1h, u16* __restrict__ w1l,
        u16* __restrict__ w2h, u16* __restrict__ w2l,
        u16* __restrict__ w3h, u16* __restrict__ w3l) {
    int t = blockIdx.x * 256 + threadIdx.x;
    if (t < 64*KP1) {
        int n = t / KP1, k = t % KP1;
        u16 h, l; splitbf((k < FIN) ? W1[(long)k*HH + n] : 0.0f, h, l);
        w1h[t] = h; w1l[t] = l;
    }
    if (t < 64*64) {
        int n = t / 64, k = t % 64;
        u16 h, l; splitbf(W2[(long)k*HH + n], h, l);
        w2h[t] = h; w2l[t] = l;
    }
    if (t < 128*64) {
        int n = t / 64, k = t % 64;
        u16 h, l; splitbf(W3[(long)k*FOUT + n], h, l);
        w3h[t] = h; w3l[t] = l;
    }
}

// ---------------------------------------------------------------------------
// Kernel 2: fused radius + PointNetConv + max-pool — byte-identical to r12
// (best measured ~523 us; barrier-free MLP, wave-slab overlay, depth-1 B-frag
// prefetch pipeline; absmax tripwire 0.015625 held r10/r11/r12).
// ---------------------------------------------------------------------------
__global__ __launch_bounds__(256) void conv_kernel(const float* __restrict__ x,
        const float* __restrict__ pos, const int* __restrict__ sel,
        const u16* __restrict__ w1h, const u16* __restrict__ w1l,
        const u16* __restrict__ w2h, const u16* __restrict__ w2l,
        const u16* __restrict__ w3h, const u16* __restrict__ w3l,
        const float* __restrict__ b1, const float* __restrict__ b2,
        const float* __restrict__ b3, float* __restrict__ xout) {
    __shared__ __align__(16) u16 fAh[64*SA], fAl[64*SA];
    __shared__ float cdv[CAND_CAP];
    __shared__ int   cixv[CAND_CAP];
    __shared__ int   snbr[KNBR];
    __shared__ float poolw[4][FOUT];
    __shared__ int   sc[2];
    const int c = blockIdx.x, t = threadIdx.x;
    const int b = c >> 11;
    const int lane = t & 63, w = t >> 6;
    const int colc = lane & 15;
    const float* pb = pos + (long)b * NPTS * 3;
    const int j0 = sel[c];
    const float qx = pb[j0*3+0], qy = pb[j0*3+1], qz = pb[j0*3+2];

    float bias1[4], bias2[4], bias3[8];
    #pragma unroll
    for (int nc = 0; nc < 4; ++nc) { bias1[nc] = b1[nc*16+colc]; bias2[nc] = b2[nc*16+colc]; }
    #pragma unroll
    for (int nc = 0; nc < 8; ++nc) bias3[nc] = b3[nc*16+colc];

    if (t == 0) { sc[0] = 0; sc[1] = 0; }
    __syncthreads();

    const float R2 = (float)(0.15 * 0.15);
    for (int it = 0; it < NPTS/256; ++it) {
        int i = t + 256*it;
        float dx = __fsub_rn(qx, pb[i*3+0]);
        float dy = __fsub_rn(qy, pb[i*3+1]);
        float dz = __fsub_rn(qz, pb[i*3+2]);
        float d2 = __fadd_rn(__fadd_rn(__fmul_rn(dx,dx), __fmul_rn(dy,dy)),
                             __fmul_rn(dz,dz));
        if (d2 <= R2) {
            int slot = atomicAdd(&sc[0], 1);
            if (slot < CAND_CAP) { cdv[slot] = d2; cixv[slot] = i; }
        }
    }
    __syncthreads();
    int C = sc[0]; if (C > CAND_CAP) C = CAND_CAP;
    int cnt;
    if (C <= KNBR) {
        for (int e = t; e < C; e += 256) snbr[e] = cixv[e];
        cnt = C;
    } else {
        for (int e = t; e < C; e += 256) {
            float de = cdv[e]; int ie = cixv[e];
            int rank = 0;
            for (int f = 0; f < C; ++f) {
                float df = cdv[f]; int jf = cixv[f];
                rank += (df < de || (df == de && jf < ie)) ? 1 : 0;
            }
            if (rank < KNBR) {
                int slot = atomicAdd(&sc[1], 1);
                snbr[slot] = ie;
            }
        }
        cnt = KNBR;
    }
    __syncthreads();

    const int kk = t >> 2, sub = t & 3;
    if (kk < cnt) {
        int j = snbr[kk];
        const float4* xr4 = (const float4*)(x + ((long)b*NPTS + j) * FEAT);
        #pragma unroll
        for (int i = 0; i < 4; ++i) {
            int ci = sub*4 + i;
            float4 v = xr4[ci];
            u16 h0,l0,h1_,l1_,h2_,l2_,h3_,l3_;
            splitbf(v.x, h0, l0); splitbf(v.y, h1_, l1_);
            splitbf(v.z, h2_, l2_); splitbf(v.w, h3_, l3_);
            int o = kk*SA + ci*4;
            fAh[o+0]=h0; fAh[o+1]=h1_; fAh[o+2]=h2_; fAh[o+3]=h3_;
            fAl[o+0]=l0; fAl[o+1]=l1_; fAl[o+2]=l2_; fAl[o+3]=l3_;
        }
        if (sub < 3) {
            float qv = (sub == 0) ? qx : ((sub == 1) ? qy : qz);
            u16 h, l; splitbf(__fsub_rn(pb[j*3+sub], qv), h, l);
            fAh[kk*SA + 64 + sub] = h; fAl[kk*SA + 64 + sub] = l;
        } else {
            fAh[kk*SA + 67] = 0; fAl[kk*SA + 67] = 0;
        }
        u32* zh = (u32*)&fAh[kk*SA + 68];
        u32* zl = (u32*)&fAl[kk*SA + 68];
        #pragma unroll
        for (int i2 = 0; i2 < 4; ++i2) { zh[sub + 4*i2] = 0; zl[sub + 4*i2] = 0; }
    }
    __threadfence_block();

    const int mrow = w * 16;
    const int mA = mrow + (lane & 15);
    const int kq = (lane >> 4) * 8;
    const int rgrp = (lane >> 4) * 4;
    const int sb = mrow * SA;

    // ---- layer 1: 96(67) -> 64, B-frag prefetch pipeline
    short8 a1h[3], a1l[3];
    #pragma unroll
    for (int i = 0; i < 3; ++i) {
        a1h[i] = *(const short8*)&fAh[mA*SA + i*32 + kq];
        a1l[i] = *(const short8*)&fAl[mA*SA + i*32 + kq];
    }
    short8 cbh[3], cbl[3], nbh[3], nbl[3];
    #pragma unroll
    for (int i = 0; i < 3; ++i) {
        cbh[i] = *(const short8*)&w1h[(0*16+colc)*KP1 + i*32 + kq];
        cbl[i] = *(const short8*)&w1l[(0*16+colc)*KP1 + i*32 + kq];
    }
    #pragma unroll
    for (int nc = 0; nc < 4; ++nc) {
        if (nc < 3) {
            int n1 = (nc+1)*16 + colc;
            #pragma unroll
            for (int i = 0; i < 3; ++i) {
                nbh[i] = *(const short8*)&w1h[n1*KP1 + i*32 + kq];
                nbl[i] = *(const short8*)&w1l[n1*KP1 + i*32 + kq];
            }
        }
        int n = nc*16 + colc;
        float bb = bias1[nc];
        f32x4 acc = {bb, bb, bb, bb};
        #pragma unroll
        for (int i = 0; i < 3; ++i)
            acc = __builtin_amdgcn_mfma_f32_16x16x32_bf16(a1h[i], cbh[i], acc, 0,0,0);
        #pragma unroll
        for (int i = 0; i < 3; ++i)
            acc = __builtin_amdgcn_mfma_f32_16x16x32_bf16(a1h[i], cbl[i], acc, 0,0,0);
        #pragma unroll
        for (int i = 0; i < 3; ++i)
            acc = __builtin_amdgcn_mfma_f32_16x16x32_bf16(a1l[i], cbh[i], acc, 0,0,0);
        #pragma unroll
        for (int r = 0; r < 4; ++r) {
            u16 h, l; splitbf(fmaxf(acc[r], 0.0f), h, l);
            int mr = rgrp + r;
            fAh[sb + mr*S2 + n] = h; fAl[sb + mr*S2 + n] = l;
        }
        #pragma unroll
        for (int i = 0; i < 3; ++i) { cbh[i] = nbh[i]; cbl[i] = nbl[i]; }
    }
    __threadfence_block();

    // ---- layer 2: 64 -> 64 (h2 overwrites same slab)
    short8 a2h[2], a2l[2];
    #pragma unroll
    for (int i = 0; i < 2; ++i) {
        a2h[i] = *(const short8*)&fAh[sb + (lane&15)*S2 + i*32 + kq];
        a2l[i] = *(const short8*)&fAl[sb + (lane&15)*S2 + i*32 + kq];
    }
    short8 c2h[2], c2l[2], n2h[2], n2l[2];
    #pragma unroll
    for (int i = 0; i < 2; ++i) {
        c2h[i] = *(const short8*)&w2h[(0*16+colc)*64 + i*32 + kq];
        c2l[i] = *(const short8*)&w2l[(0*16+colc)*64 + i*32 + kq];
    }
    #pragma unroll
    for (int nc = 0; nc < 4; ++nc) {
        if (nc < 3) {
            int n1 = (nc+1)*16 + colc;
            #pragma unroll
            for (int i = 0; i < 2; ++i) {
                n2h[i] = *(const short8*)&w2h[n1*64 + i*32 + kq];
                n2l[i] = *(const short8*)&w2l[n1*64 + i*32 + kq];
            }
        }
        int n = nc*16 + colc;
        float bb = bias2[nc];
        f32x4 acc = {bb, bb, bb, bb};
        #pragma unroll
        for (int i = 0; i < 2; ++i)
            acc = __builtin_amdgcn_mfma_f32_16x16x32_bf16(a2h[i], c2h[i], acc, 0,0,0);
        #pragma unroll
        for (int i = 0; i < 2; ++i)
            acc = __builtin_amdgcn_mfma_f32_16x16x32_bf16(a2h[i], c2l[i], acc, 0,0,0);
        #pragma unroll
        for (int i = 0; i < 2; ++i)
            acc = __builtin_amdgcn_mfma_f32_16x16x32_bf16(a2l[i], c2h[i], acc, 0,0,0);
        #pragma unroll
        for (int r = 0; r < 4; ++r) {
            u16 h, l; splitbf(fmaxf(acc[r], 0.0f), h, l);
            int mr = rgrp + r;
            fAh[sb + mr*S2 + n] = h; fAl[sb + mr*S2 + n] = l;
        }
        #pragma unroll
        for (int i = 0; i < 2; ++i) { c2h[i] = n2h[i]; c2l[i] = n2l[i]; }
    }
    __threadfence_block();

    // ---- layer 3: 64 -> 128 + fused relu + masked max-pool
    short8 a3h[2], a3l[2];
    #pragma unroll
    for (int i = 0; i < 2; ++i) {
        a3h[i] = *(const short8*)&fAh[sb + (lane&15)*S2 + i*32 + kq];
        a3l[i] = *(const short8*)&fAl[sb + (lane&15)*S2 + i*32 + kq];
    }
    short8 c3h[2], c3l[2], n3h[2], n3l[2];
    #pragma unroll
    for (int i = 0; i < 2; ++i) {
        c3h[i] = *(const short8*)&w3h[(0*16+colc)*64 + i*32 + kq];
        c3l[i] = *(const short8*)&w3l[(0*16+colc)*64 + i*32 + kq];
    }
    #pragma unroll
    for (int nc = 0; nc < 8; ++nc) {
        if (nc < 7) {
            int n1 = (nc+1)*16 + colc;
            #pragma unroll
            for (int i = 0; i < 2; ++i) {
                n3h[i] = *(const short8*)&w3h[n1*64 + i*32 + kq];
                n3l[i] = *(const short8*)&w3l[n1*64 + i*32 + kq];
            }
        }
        int n = nc*16 + colc;
        float bb = bias3[nc];
        f32x4 acc = {bb, bb, bb, bb};
        #pragma unroll
        for (int i = 0; i < 2; ++i)
            acc = __builtin_amdgcn_mfma_f32_16x16x32_bf16(a3h[i], c3h[i], acc, 0,0,0);
        #pragma unroll
        for (int i = 0; i < 2; ++i)
            acc = __builtin_amdgcn_mfma_f32_16x16x32_bf16(a3h[i], c3l[i], acc, 0,0,0);
        #pragma unroll
        for (int i = 0; i < 2; ++i)
            acc = __builtin_amdgcn_mfma_f32_16x16x32_bf16(a3l[i], c3h[i], acc, 0,0,0);
        float v = 0.0f;
        #pragma unroll
        for (int r = 0; r < 4; ++r) {
            int m = mrow + rgrp + r;
            float hv = fmaxf(acc[r], 0.0f);
            v = (m < cnt) ? fmaxf(v, hv) : v;
        }
        v = fmaxf(v, __shfl_xor(v, 16, 64));
        v = fmaxf(v, __shfl_xor(v, 32, 64));
        if (lane < 16) poolw[w][nc*16 + lane] = v;
        #pragma unroll
        for (int i = 0; i < 2; ++i) { c3h[i] = n3h[i]; c3l[i] = n3l[i]; }
    }
    __syncthreads();
    if (t < FOUT) {
        float v = fmaxf(fmaxf(poolw[0][t], poolw[1][t]),
                        fmaxf(poolw[2][t], poolw[3][t]));
        xout[(long)c*FOUT + t] = v;
    }
}

// ---------------------------------------------------------------------------
extern "C" void kernel_launch(void* const* d_in, const int* in_sizes, int n_in,
                              void* d_out, int out_size, void* d_ws, size_t ws_size,
                              hipStream_t stream) {
    const float* x   = (const float*)d_in[0];
    const float* pos = (const float*)d_in[1];
    const float* W1 = (const float*)d_in[3];
    const float* b1 = (const float*)d_in[4];
    const float* W2 = (const float*)d_in[5];
    const float* b2 = (const float*)d_in[6];
    const float* W3 = (const float*)d_in[7];
    const float* b3 = (const float*)d_in[8];

    float* out       = (float*)d_out;
    float* xout      = out;
    float* pos_out   = out + (long)NCENT * FOUT;
    float* batch_out = pos_out + (long)NCENT * 3;

    int* sel = (int*)d_ws;
    u16* w1h = (u16*)((char*)d_ws + 65536);
    u16* w1l = w1h + 64*KP1;
    u16* w2h = w1l + 64*KP1;
    u16* w2l = w2h + 64*64;
    u16* w3h = w2l + 64*64;
    u16* w3l = w3h + 128*64;

    wcvt_kernel<<<32, 256, 0, stream>>>(W1, W2, W3, w1h, w1l, w2h, w2l, w3h, w3l);
    fps_kernel<<<NB, 256, 0, stream>>>(pos, sel, pos_out, batch_out);
    conv_kernel<<<NCENT, 256, 0, stream>>>(x, pos, sel, w1h, w1l, w2h, w2l,
                                           w3h, w3l, b1, b2, b3, xout);
}

// Round 14
// 1955.950 us; speedup vs baseline: 1.4626x; 1.1245x over previous
//
#include <hip/hip_runtime.h>

typedef unsigned short u16;
typedef unsigned int u32;
typedef unsigned long long u64;

#define NB 8
#define NPTS 4096
#define MSEL 2048
#define NCENT (NB*MSEL)
#define KNBR 64
#define FEAT 64
#define FIN 67
#define HH 64
#define FOUT 128
#define CAND_CAP 192

#define KP1 96     // layer-1 K padded to 3x32
#define SA 104     // feat A-buffer row stride (bf16 elems)
#define S2 72      // h1/h2 row stride

typedef __attribute__((ext_vector_type(8))) short short8;
typedef __attribute__((ext_vector_type(4))) float f32x4;

__device__ __forceinline__ float bf2f(u16 u) {
    union { u32 i; float f; } v; v.i = ((u32)u) << 16; return v.f;
}
__device__ __forceinline__ u16 f2bf(float f) {
    union { float f; u32 i; } v; v.f = f;
    u32 x = v.i;
    x += 0x7fffu + ((x >> 16) & 1u);
    return (u16)(x >> 16);
}
__device__ __forceinline__ void splitbf(float a, u16& hi, u16& lo) {
    u16 h = f2bf(a);
    hi = h;
    lo = f2bf(__fsub_rn(a, bf2f(h)));
}

// ---------------------------------------------------------------------------
// DPP wave-64 reductions (verified r7-r13).
// ---------------------------------------------------------------------------
__device__ __forceinline__ int wave_max_i(int v) {
    int u;
    u = __builtin_amdgcn_update_dpp(v, v, 0x111, 0xf, 0xf, false); v = max(v, u);
    u = __builtin_amdgcn_update_dpp(v, v, 0x112, 0xf, 0xf, false); v = max(v, u);
    u = __builtin_amdgcn_update_dpp(v, v, 0x114, 0xf, 0xf, false); v = max(v, u);
    u = __builtin_amdgcn_update_dpp(v, v, 0x118, 0xf, 0xf, false); v = max(v, u);
    u = __builtin_amdgcn_update_dpp(v, v, 0x142, 0xf, 0xf, false); v = max(v, u);
    u = __builtin_amdgcn_update_dpp(v, v, 0x143, 0xf, 0xf, false); v = max(v, u);
    return __builtin_amdgcn_readlane(v, 63);
}
__device__ __forceinline__ int wave_min_i(int v) {
    int u;
    u = __builtin_amdgcn_update_dpp(v, v, 0x111, 0xf, 0xf, false); v = min(v, u);
    u = __builtin_amdgcn_update_dpp(v, v, 0x112, 0xf, 0xf, false); v = min(v, u);
    u = __builtin_amdgcn_update_dpp(v, v, 0x114, 0xf, 0xf, false); v = min(v, u);
    u = __builtin_amdgcn_update_dpp(v, v, 0x118, 0xf, 0xf, false); v = min(v, u);
    u = __builtin_amdgcn_update_dpp(v, v, 0x142, 0xf, 0xf, false); v = min(v, u);
    u = __builtin_amdgcn_update_dpp(v, v, 0x143, 0xf, 0xf, false); v = min(v, u);
    return __builtin_amdgcn_readlane(v, 63);
}

// ---------------------------------------------------------------------------
// Kernel 1: exact FPS — byte-identical to r13 (best measured: 1611 us).
// ---------------------------------------------------------------------------
__global__ __launch_bounds__(256) void fps_kernel(const float* __restrict__ pos,
        int* __restrict__ sel, float* __restrict__ pos_out,
        float* __restrict__ batch_out) {
    __shared__ float px[NPTS], py[NPTS], pz[NPTS];
    __shared__ int hist[MSEL];
    __shared__ int4  sA[2][4];    // {M, I, xbits, ybits} per wave
    __shared__ float sZ[2][4];
    const int b = blockIdx.x, t = threadIdx.x;
    const int wid = t >> 6;
    const float* pb = pos + (long)b * NPTS * 3;

    for (int i = t; i < NPTS; i += 256) {
        px[i] = pb[i*3+0]; py[i] = pb[i*3+1]; pz[i] = pb[i*3+2];
    }
    __syncthreads();

    float rx[16], ry[16], rz[16], md[16];
    #pragma unroll
    for (int j = 0; j < 16; ++j) {
        int i = t + 256*j;
        rx[j] = px[i]; ry[j] = py[i]; rz[j] = pz[i];
        md[j] = __builtin_inff();
    }

    int cur = 0;
    float cx = px[0], cy = py[0], cz = pz[0];
    for (int s = 0; s < MSEL; ++s) {
        const int p = s & 1;
        if (t == 0) hist[s] = cur;
        float bv = -1.0f; int bi = 0;
        #pragma unroll
        for (int j = 0; j < 16; ++j) {
            float dx = __fsub_rn(rx[j], cx);
            float dy = __fsub_rn(ry[j], cy);
            float dz = __fsub_rn(rz[j], cz);
            float d  = __fadd_rn(__fadd_rn(__fmul_rn(dx,dx), __fmul_rn(dy,dy)),
                                 __fmul_rn(dz,dz));
            float m = fminf(md[j], d);
            md[j] = m;
            if (m > bv) { bv = m; bi = t + 256*j; }   // strict >: first occurrence
        }
        const int fb = (int)__float_as_uint(bv);       // bv >= 0 -> int-ordered
        const int Mw = wave_max_i(fb);
        const int cnd = (fb == Mw) ? bi : 0x7fffffff;
        const int Iw = wave_min_i(cnd);                // wave argmax, min index
        if (t == (Iw & 255)) {                         // owner carries coords
            int j = Iw >> 8;
            sA[p][wid] = make_int4(Mw, Iw, __float_as_int(rx[j]),
                                   __float_as_int(ry[j]));
            sZ[p][wid] = rz[j];
        }
        __syncthreads();
        int4 v0 = sA[p][0];
        int M = v0.x, I = v0.y;
        float nx = __int_as_float(v0.z), ny = __int_as_float(v0.w), nz = sZ[p][0];
        #pragma unroll
        for (int w = 1; w < 4; ++w) {
            int4 vw = sA[p][w];
            if (vw.x > M || (vw.x == M && vw.y < I)) {
                M = vw.x; I = vw.y;
                nx = __int_as_float(vw.z); ny = __int_as_float(vw.w);
                nz = sZ[p][w];
            }
        }
        cur = I; cx = nx; cy = ny; cz = nz;
    }
    __syncthreads();
    for (int g = t; g < MSEL; g += 256) {
        int i = hist[g];
        int o = b * MSEL + g;
        sel[o] = i;
        pos_out[o*3+0] = px[i]; pos_out[o*3+1] = py[i]; pos_out[o*3+2] = pz[i];
        batch_out[o] = (float)b;
    }
}

// ---------------------------------------------------------------------------
// Kernel 1.5: weight pre-transform (unchanged, verified).
// ---------------------------------------------------------------------------
__global__ __launch_bounds__(256) void wcvt_kernel(const float* __restrict__ W1,
        const float* __restrict__ W2, const float* __restrict__ W3,
        u16* __restrict__ w1h, u16* __restrict__ w1l,
        u16* __restrict__ w2h, u16* __restrict__ w2l,
        u16* __restrict__ w3h, u16* __restrict__ w3l) {
    int t = blockIdx.x * 256 + threadIdx.x;
    if (t < 64*KP1) {
        int n = t / KP1, k = t % KP1;
        u16 h, l; splitbf((k < FIN) ? W1[(long)k*HH + n] : 0.0f, h, l);
        w1h[t] = h; w1l[t] = l;
    }
    if (t < 64*64) {
        int n = t / 64, k = t % 64;
        u16 h, l; splitbf(W2[(long)k*HH + n], h, l);
        w2h[t] = h; w2l[t] = l;
    }
    if (t < 128*64) {
        int n = t / 64, k = t % 64;
        u16 h, l; splitbf(W3[(long)k*FOUT + n], h, l);
        w3h[t] = h; w3l[t] = l;
    }
}

// ---------------------------------------------------------------------------
// Kernel 2: fused radius + PointNetConv + max-pool, COLUMN-PARTITIONED waves.
// Wave w processes ALL 64 rows for its 16-col stripe (layer3: 2 stripes), so
// each wave reads only its own B-columns: block weight traffic drops 288 ->
// 72 KB (one copy). Cross-wave column dependence between layers -> 2 extra
// __syncthreads. Pool completes in-wave (masked max over row-tiles + 2
// shfl_xor), direct xout write. Per-element MFMA arithmetic bit-identical to
// r12/r13 (absmax tripwire: exactly 0.015625).
// ---------------------------------------------------------------------------
__global__ __launch_bounds__(256) void conv_kernel(const float* __restrict__ x,
        const float* __restrict__ pos, const int* __restrict__ sel,
        const u16* __restrict__ w1h, const u16* __restrict__ w1l,
        const u16* __restrict__ w2h, const u16* __restrict__ w2l,
        const u16* __restrict__ w3h, const u16* __restrict__ w3l,
        const float* __restrict__ b1, const float* __restrict__ b2,
        const float* __restrict__ b3, float* __restrict__ xout) {
    __shared__ __align__(16) u16 fAh[64*SA], fAl[64*SA];   // feat, then h2 (stride S2)
    __shared__ __align__(16) u16 h1h[64*S2], h1l[64*S2];
    __shared__ float cdv[CAND_CAP];
    __shared__ int   cixv[CAND_CAP];
    __shared__ int   snbr[KNBR];
    __shared__ int   sc[2];
    const int c = blockIdx.x, t = threadIdx.x;
    const int b = c >> 11;
    const int lane = t & 63, w = t >> 6;
    const int colc = lane & 15;
    const float* pb = pos + (long)b * NPTS * 3;
    const int j0 = sel[c];
    const float qx = pb[j0*3+0], qy = pb[j0*3+1], qz = pb[j0*3+2];

    const int nw = w*16 + colc;            // this wave's column (layers 1-2)
    const float bias1 = b1[nw];
    const float bias2 = b2[nw];
    const float bias3[2] = { b3[(2*w+0)*16 + colc], b3[(2*w+1)*16 + colc] };

    if (t == 0) { sc[0] = 0; sc[1] = 0; }
    __syncthreads();

    // ---- radius gather (bit-exact; verified r4-r13)
    const float R2 = (float)(0.15 * 0.15);
    for (int it = 0; it < NPTS/256; ++it) {
        int i = t + 256*it;
        float dx = __fsub_rn(qx, pb[i*3+0]);
        float dy = __fsub_rn(qy, pb[i*3+1]);
        float dz = __fsub_rn(qz, pb[i*3+2]);
        float d2 = __fadd_rn(__fadd_rn(__fmul_rn(dx,dx), __fmul_rn(dy,dy)),
                             __fmul_rn(dz,dz));
        if (d2 <= R2) {
            int slot = atomicAdd(&sc[0], 1);
            if (slot < CAND_CAP) { cdv[slot] = d2; cixv[slot] = i; }
        }
    }
    __syncthreads();
    int C = sc[0]; if (C > CAND_CAP) C = CAND_CAP;
    int cnt;
    if (C <= KNBR) {
        for (int e = t; e < C; e += 256) snbr[e] = cixv[e];
        cnt = C;
    } else {
        for (int e = t; e < C; e += 256) {
            float de = cdv[e]; int ie = cixv[e];
            int rank = 0;
            for (int f = 0; f < C; ++f) {
                float df = cdv[f]; int jf = cixv[f];
                rank += (df < de || (df == de && jf < ie)) ? 1 : 0;
            }
            if (rank < KNBR) {
                int slot = atomicAdd(&sc[1], 1);
                snbr[slot] = ie;
            }
        }
        cnt = KNBR;
    }
    __syncthreads();

    // ---- stage features (4 threads/row); zero K-pad cols 67..99
    const int kk = t >> 2, sub = t & 3;
    if (kk < cnt) {
        int j = snbr[kk];
        const float4* xr4 = (const float4*)(x + ((long)b*NPTS + j) * FEAT);
        #pragma unroll
        for (int i = 0; i < 4; ++i) {
            int ci = sub*4 + i;
            float4 v = xr4[ci];
            u16 h0,l0,h1_,l1_,h2_,l2_,h3_,l3_;
            splitbf(v.x, h0, l0); splitbf(v.y, h1_, l1_);
            splitbf(v.z, h2_, l2_); splitbf(v.w, h3_, l3_);
            int o = kk*SA + ci*4;
            fAh[o+0]=h0; fAh[o+1]=h1_; fAh[o+2]=h2_; fAh[o+3]=h3_;
            fAl[o+0]=l0; fAl[o+1]=l1_; fAl[o+2]=l2_; fAl[o+3]=l3_;
        }
        if (sub < 3) {
            float qv = (sub == 0) ? qx : ((sub == 1) ? qy : qz);
            u16 h, l; splitbf(__fsub_rn(pb[j*3+sub], qv), h, l);
            fAh[kk*SA + 64 + sub] = h; fAl[kk*SA + 64 + sub] = l;
        } else {
            fAh[kk*SA + 67] = 0; fAl[kk*SA + 67] = 0;
        }
        u32* zh = (u32*)&fAh[kk*SA + 68];
        u32* zl = (u32*)&fAl[kk*SA + 68];
        #pragma unroll
        for (int i2 = 0; i2 < 4; ++i2) { zh[sub + 4*i2] = 0; zl[sub + 4*i2] = 0; }
    }
    __syncthreads();   // layer 1 reads ALL rows -> full barrier

    const int mL = lane & 15;              // A-row within a 16-row tile
    const int kq = (lane >> 4) * 8;
    const int rgrp = (lane >> 4) * 4;

    // ---- B-fragment loads: this wave's column stripe only (18 KB/wave)
    short8 B1h[3], B1l[3], B2h[2], B2l[2], B3h[2][2], B3l[2][2];
    #pragma unroll
    for (int i = 0; i < 3; ++i) {
        B1h[i] = *(const short8*)&w1h[nw*KP1 + i*32 + kq];
        B1l[i] = *(const short8*)&w1l[nw*KP1 + i*32 + kq];
    }
    #pragma unroll
    for (int i = 0; i < 2; ++i) {
        B2h[i] = *(const short8*)&w2h[nw*64 + i*32 + kq];
        B2l[i] = *(const short8*)&w2l[nw*64 + i*32 + kq];
    }

    // ---- layer 1: 96(67) -> 64, all 4 row-tiles, cols nw
    #pragma unroll
    for (int rt = 0; rt < 4; ++rt) {
        short8 ah[3], al[3];
        #pragma unroll
        for (int i = 0; i < 3; ++i) {
            ah[i] = *(const short8*)&fAh[(rt*16 + mL)*SA + i*32 + kq];
            al[i] = *(const short8*)&fAl[(rt*16 + mL)*SA + i*32 + kq];
        }
        f32x4 acc = {bias1, bias1, bias1, bias1};
        #pragma unroll
        for (int i = 0; i < 3; ++i)
            acc = __builtin_amdgcn_mfma_f32_16x16x32_bf16(ah[i], B1h[i], acc, 0,0,0);
        #pragma unroll
        for (int i = 0; i < 3; ++i)
            acc = __builtin_amdgcn_mfma_f32_16x16x32_bf16(ah[i], B1l[i], acc, 0,0,0);
        #pragma unroll
        for (int i = 0; i < 3; ++i)
            acc = __builtin_amdgcn_mfma_f32_16x16x32_bf16(al[i], B1h[i], acc, 0,0,0);
        #pragma unroll
        for (int r = 0; r < 4; ++r) {
            u16 h, l; splitbf(fmaxf(acc[r], 0.0f), h, l);
            int mr = rt*16 + rgrp + r;
            h1h[mr*S2 + nw] = h; h1l[mr*S2 + nw] = l;
        }
    }
    // prefetch layer-3 B while layer-1 results drain
    #pragma unroll
    for (int j = 0; j < 2; ++j) {
        int n3 = (2*w + j)*16 + colc;
        #pragma unroll
        for (int i = 0; i < 2; ++i) {
            B3h[j][i] = *(const short8*)&w3h[n3*64 + i*32 + kq];
            B3l[j][i] = *(const short8*)&w3l[n3*64 + i*32 + kq];
        }
    }
    __syncthreads();

    // ---- layer 2: 64 -> 64 (h2 overwrites fA, stride S2)
    #pragma unroll
    for (int rt = 0; rt < 4; ++rt) {
        short8 ah[2], al[2];
        #pragma unroll
        for (int i = 0; i < 2; ++i) {
            ah[i] = *(const short8*)&h1h[(rt*16 + mL)*S2 + i*32 + kq];
            al[i] = *(const short8*)&h1l[(rt*16 + mL)*S2 + i*32 + kq];
        }
        f32x4 acc = {bias2, bias2, bias2, bias2};
        #pragma unroll
        for (int i = 0; i < 2; ++i)
            acc = __builtin_amdgcn_mfma_f32_16x16x32_bf16(ah[i], B2h[i], acc, 0,0,0);
        #pragma unroll
        for (int i = 0; i < 2; ++i)
            acc = __builtin_amdgcn_mfma_f32_16x16x32_bf16(ah[i], B2l[i], acc, 0,0,0);
        #pragma unroll
        for (int i = 0; i < 2; ++i)
            acc = __builtin_amdgcn_mfma_f32_16x16x32_bf16(al[i], B2h[i], acc, 0,0,0);
        #pragma unroll
        for (int r = 0; r < 4; ++r) {
            u16 h, l; splitbf(fmaxf(acc[r], 0.0f), h, l);
            int mr = rt*16 + rgrp + r;
            fAh[mr*S2 + nw] = h; fAl[mr*S2 + nw] = l;
        }
    }
    __syncthreads();

    // ---- layer 3: 64 -> 128, 2 col stripes/wave, fused relu + masked pool
    #pragma unroll
    for (int j = 0; j < 2; ++j) {
        const float bb = bias3[j];
        float v = 0.0f;   // relu >= 0 and cnt >= 1 -> 0 is identity
        #pragma unroll
        for (int rt = 0; rt < 4; ++rt) {
            short8 ah[2], al[2];
            #pragma unroll
            for (int i = 0; i < 2; ++i) {
                ah[i] = *(const short8*)&fAh[(rt*16 + mL)*S2 + i*32 + kq];
                al[i] = *(const short8*)&fAl[(rt*16 + mL)*S2 + i*32 + kq];
            }
            f32x4 acc = {bb, bb, bb, bb};
            #pragma unroll
            for (int i = 0; i < 2; ++i)
                acc = __builtin_amdgcn_mfma_f32_16x16x32_bf16(ah[i], B3h[j][i], acc, 0,0,0);
            #pragma unroll
            for (int i = 0; i < 2; ++i)
                acc = __builtin_amdgcn_mfma_f32_16x16x32_bf16(ah[i], B3l[j][i], acc, 0,0,0);
            #pragma unroll
            for (int i = 0; i < 2; ++i)
                acc = __builtin_amdgcn_mfma_f32_16x16x32_bf16(al[i], B3h[j][i], acc, 0,0,0);
            #pragma unroll
            for (int r = 0; r < 4; ++r) {
                int m = rt*16 + rgrp + r;
                float hv = fmaxf(acc[r], 0.0f);
                v = (m < cnt) ? fmaxf(v, hv) : v;
            }
        }
        v = fmaxf(v, __shfl_xor(v, 16, 64));
        v = fmaxf(v, __shfl_xor(v, 32, 64));
        if (lane < 16)
            xout[(long)c*FOUT + (2*w + j)*16 + lane] = v;
    }
}

// ---------------------------------------------------------------------------
extern "C" void kernel_launch(void* const* d_in, const int* in_sizes, int n_in,
                              void* d_out, int out_size, void* d_ws, size_t ws_size,
                              hipStream_t stream) {
    const float* x   = (const float*)d_in[0];
    const float* pos = (const float*)d_in[1];
    const float* W1 = (const float*)d_in[3];
    const float* b1 = (const float*)d_in[4];
    const float* W2 = (const float*)d_in[5];
    const float* b2 = (const float*)d_in[6];
    const float* W3 = (const float*)d_in[7];
    const float* b3 = (const float*)d_in[8];

    float* out       = (float*)d_out;
    float* xout      = out;
    float* pos_out   = out + (long)NCENT * FOUT;
    float* batch_out = pos_out + (long)NCENT * 3;

    int* sel = (int*)d_ws;
    u16* w1h = (u16*)((char*)d_ws + 65536);
    u16* w1l = w1h + 64*KP1;
    u16* w2h = w1l + 64*KP1;
    u16* w2l = w2h + 64*64;
    u16* w3h = w2l + 64*64;
    u16* w3l = w3h + 128*64;

    wcvt_kernel<<<32, 256, 0, stream>>>(W1, W2, W3, w1h, w1l, w2h, w2l, w3h, w3l);
    fps_kernel<<<NB, 256, 0, stream>>>(pos, sel, pos_out, batch_out);
    conv_kernel<<<NCENT, 256, 0, stream>>>(x, pos, sel, w1h, w1l, w2h, w2l,
                                           w3h, w3l, b1, b2, b3, xout);
}